// Round 8
// baseline (275.169 us; speedup 1.0000x reference)
//
#include <hip/hip_runtime.h>
#include <hip/hip_bf16.h>

// ---- problem constants ----
#define BB   2
#define NT   64
#define NC   1024
#define NN   1024
#define NTOK (NT + NC + NN)   // 2112
#define CC   1024
#define HH   16
#define HD   64
#define K3   (3 * CC)
#define EPSV 1e-5f

typedef __attribute__((ext_vector_type(8))) short short8;
typedef __attribute__((ext_vector_type(4))) float f32x4;
typedef __attribute__((ext_vector_type(4))) float float4v;

__device__ __forceinline__ short bf16raw(float x) {
    __hip_bfloat16 h = __float2bfloat16(x);
    return *(short*)&h;
}

#define GL_LDS(gptr, lptr) \
    __builtin_amdgcn_global_load_lds( \
        (const __attribute__((address_space(1))) void*)(gptr), \
        (__attribute__((address_space(3))) void*)(lptr), 16, 0, 0)

// counted-vmcnt barrier pair (gemm_qkv only — pays when loads/step is large)
#define WAIT_VM(N) asm volatile("s_waitcnt vmcnt(" #N ")" ::: "memory")
#define BARRIER_FENCED() do { __builtin_amdgcn_s_barrier(); \
                              asm volatile("" ::: "memory"); } while (0)
#define FENCE_BARRIER()  do { asm volatile("" ::: "memory"); \
                              __builtin_amdgcn_s_barrier(); } while (0)

// split-K chunk tables (file-scope __constant__)
__constant__ signed char QB_tab[33] =
    {16,16,16,15,15,15,14,14,14,13,13,13,12,12,12,11,11,10,10,9,9,8,8,7,7,6,6,5,4,3,2,1,0};
__constant__ signed char CH_tab[33] =
    { 0, 1, 2, 0, 1, 2, 0, 1, 2, 0, 1, 2, 0, 1, 2, 0, 1, 0, 1,0,1,0,1,0,1,0,1,0,0,0,0,0,0};

// ---------------- merged cast fp32 -> bf16 (vectorized x4) ----------------
__global__ __launch_bounds__(256) void cast_all(
    const float* __restrict__ s0, const float* __restrict__ s1, const float* __restrict__ s2,
    __hip_bfloat16* __restrict__ d0, __hip_bfloat16* __restrict__ d1, __hip_bfloat16* __restrict__ d2,
    int n0, int n1, int n2)   // counts in float4 units
{
    int i = blockIdx.x * 256 + threadIdx.x;
    int stride = gridDim.x * 256;
    int ntot = n0 + n1 + n2;
    for (; i < ntot; i += stride) {
        const float* sp; short* dp; int j;
        if (i < n0)            { sp = s0; dp = (short*)d0; j = i; }
        else if (i < n0 + n1)  { sp = s1; dp = (short*)d1; j = i - n0; }
        else                   { sp = s2; dp = (short*)d2; j = i - n0 - n1; }
        float4v v = *(const float4v*)(sp + (size_t)j * 4);
        short4 o;
        o.x = bf16raw(v.x); o.y = bf16raw(v.y); o.z = bf16raw(v.z); o.w = bf16raw(v.w);
        *(short4*)(dp + (size_t)j * 4) = o;
    }
}

// ---------------- QKV GEMM 128x128, BK=64 swizzled, counted-vmcnt dbuf ----
// + fused LN/RoPE/V-transpose epilogue
// NOTE: Q is scaled by 0.125 * log2(e) so attention can use exp2 directly.
__global__ __launch_bounds__(256) void gemm_qkv(
    const __hip_bfloat16* __restrict__ A,     // (BB*NTOK, CC) bf16
    const __hip_bfloat16* __restrict__ Wb,    // (3, K3, CC) bf16
    const float* __restrict__ biasb,          // (3, K3)
    const float* __restrict__ qn_w, const float* __restrict__ qn_b,
    const float* __restrict__ kn_w, const float* __restrict__ kn_b,
    __hip_bfloat16* __restrict__ Q,           // (BB*HH, NTOK, HD)
    __hip_bfloat16* __restrict__ Kg,
    __hip_bfloat16* __restrict__ Vt)          // (BB*HH, HD, NTOK)
{
    // 64KB: buffer b at b*16384 shorts: [As 8192 | Bs 8192]
    __shared__ short lds[32768];
    short* buf = lds;   // epilogue scratch (128*134 = 17152 shorts, overlaid)

    int tid = threadIdx.x;
    int lane = tid & 63, w = tid >> 6;
    int l15 = lane & 15, quad = lane >> 4;
    int wm = w >> 1, wn = w & 1;
    int r7 = l15 & 7;

    int y = blockIdx.y;
    int seg, tm;
    if (y < 16)      { seg = 1; tm = y * 128; }
    else if (y < 32) { seg = 2; tm = (y - 16) * 128; }
    else             { seg = 0; tm = 0; }
    int S = (seg == 0) ? 64 : 1024;
    int seg_start = (seg == 0) ? 0 : (seg == 1 ? NT : NT + NC);
    const short* W = (const short*)Wb + (size_t)seg * K3 * CC;
    const float* bias = biasb + (size_t)seg * K3;
    int tileN = blockIdx.x * 128;

    const short* aptr[4];
    const short* bptr[4];
#pragma unroll
    for (int j = 0; j < 4; ++j) {
        int c = j * 256 + tid;
        int row = c >> 3, u = (c & 7) ^ (row & 7);
        int ar = tm + row;
        int arow = (ar / S) * NTOK + seg_start + (ar % S);
        aptr[j] = (const short*)A + (size_t)arow * CC + u * 8;
        bptr[j] = W + (size_t)(tileN + row) * CC + u * 8;
    }

    f32x4 zero = {0.f, 0.f, 0.f, 0.f};
    f32x4 acc[4][4];
#pragma unroll
    for (int mb = 0; mb < 4; ++mb)
#pragma unroll
        for (int nb = 0; nb < 4; ++nb) acc[mb][nb] = zero;

    // prologue: stage K-tile 0 into buffer 0; full drain resets compiler vm-model
#pragma unroll
    for (int j = 0; j < 4; ++j) {
        int c8 = (j * 256 + tid) * 8;
        GL_LDS(aptr[j], lds + c8);
        GL_LDS(bptr[j], lds + 8192 + c8);
    }
    __syncthreads();

    for (int t = 0; t < 16; ++t) {
        short* As = lds + (t & 1) * 16384;
        short* Bs = As + 8192;
        if (t < 15) {   // prefetch tile t+1 into the other buffer; stays in flight
            short* An = lds + ((t + 1) & 1) * 16384;
            int k0 = (t + 1) * 64;
#pragma unroll
            for (int j = 0; j < 4; ++j) {
                int c8 = (j * 256 + tid) * 8;
                GL_LDS(aptr[j] + k0, An + c8);
                GL_LDS(bptr[j] + k0, An + 8192 + c8);
            }
            WAIT_VM(8);       // tile-t loads (oldest 8) landed; t+1's 8 in flight
        } else {
            WAIT_VM(0);
        }
        BARRIER_FENCED();     // all waves: tile t visible

#pragma unroll
        for (int s = 0; s < 2; ++s) {
            int sx = ((s * 4 + quad) ^ r7) * 8;
            short8 af[4], bf[4];
#pragma unroll
            for (int mb = 0; mb < 4; ++mb)
                af[mb] = *(const short8*)&As[(wm * 64 + mb * 16 + l15) * 64 + sx];
#pragma unroll
            for (int nb = 0; nb < 4; ++nb)
                bf[nb] = *(const short8*)&Bs[(wn * 64 + nb * 16 + l15) * 64 + sx];
#pragma unroll
            for (int mb = 0; mb < 4; ++mb)
#pragma unroll
                for (int nb = 0; nb < 4; ++nb)
                    acc[mb][nb] = __builtin_amdgcn_mfma_f32_16x16x32_bf16(af[mb], bf[nb], acc[mb][nb], 0, 0, 0);
        }
        FENCE_BARRIER();      // all waves done reading buf[t&1] before overwrite
    }

    int sect = tileN >> 10;                    // 0=Q, 1=K, 2=V

    if (sect < 2) {
        const float* nw = (sect == 0 ? qn_w : kn_w) + seg * HD;
        const float* nbv = (sect == 0 ? qn_b : kn_b) + seg * HD;
        float lw[4], lb[4], bcol[4];
#pragma unroll
        for (int nb = 0; nb < 4; ++nb) {
            lw[nb] = nw[nb * 16 + l15];
            lb[nb] = nbv[nb * 16 + l15];
            bcol[nb] = bias[tileN + wn * 64 + nb * 16 + l15];
        }
        // 0.125 * log2(e): attention uses exp2
        float qscale = (sect == 0) ? 0.18033688011112042f : 1.0f;

        float invf0 = expf(-9.210340371976184f * (float)l15 * (1.0f / 32.0f));
        float invf1 = expf(-9.210340371976184f * (float)(16 + l15) * (1.0f / 32.0f));
        float cd0, sd0, cd1, sd1;
        sincosf(invf0, &sd0, &cd0);   // unit-step rotation
        sincosf(invf1, &sd1, &cd1);

#pragma unroll
        for (int mb = 0; mb < 4; ++mb) {
            // pos for r=0 of this (mb, quad) group; r=0..3 tokens are consecutive
            int tok0 = wm * 64 + mb * 16 + quad * 4;
            int ar0 = tm + tok0;
            int nloc0 = ar0 % S;                           // local within segment
            int pos0 = (seg == 0) ? nloc0 : (seg_start + nloc0 - NT);
            float c0, s0, c1, s1v;
            sincosf((float)pos0 * invf0, &s0, &c0);
            sincosf((float)pos0 * invf1, &s1v, &c1);

#pragma unroll
            for (int r = 0; r < 4; ++r) {
                int tok = tok0 + r;
                float v[4];
#pragma unroll
                for (int nb = 0; nb < 4; ++nb) v[nb] = acc[mb][nb][r] + bcol[nb];

                // one-pass LN: reduce (sum, sumsq) together
                float t1 = v[0] + v[1] + v[2] + v[3];
                float t2 = v[0] * v[0] + v[1] * v[1] + v[2] * v[2] + v[3] * v[3];
#pragma unroll
                for (int off = 8; off >= 1; off >>= 1) {
                    t1 += __shfl_xor(t1, off);
                    t2 += __shfl_xor(t2, off);
                }
                float mu = t1 * (1.0f / 64.0f);
                float var = t2 * (1.0f / 64.0f) - mu * mu;
                float rstd = rsqrtf(var + EPSV);
#pragma unroll
                for (int nb = 0; nb < 4; ++nb) v[nb] = (v[nb] - mu) * rstd * lw[nb] + lb[nb];

                short* bp = &buf[tok * 134 + wn * 64];
                bp[0 * 16 + l15] = bf16raw((v[0] * c0 - v[2] * s0) * qscale);
                bp[1 * 16 + l15] = bf16raw((v[1] * c1 - v[3] * s1v) * qscale);
                bp[2 * 16 + l15] = bf16raw((v[2] * c0 + v[0] * s0) * qscale);
                bp[3 * 16 + l15] = bf16raw((v[3] * c1 + v[1] * s1v) * qscale);

                // advance rotation to next consecutive position
                float nc0 = c0 * cd0 - s0 * sd0, ns0 = s0 * cd0 + c0 * sd0;
                float nc1 = c1 * cd1 - s1v * sd1, ns1 = s1v * cd1 + c1 * sd1;
                c0 = nc0; s0 = ns0; c1 = nc1; s1v = ns1;
            }
        }
        __syncthreads();
        __hip_bfloat16* dst = (sect == 0) ? Q : Kg;
        int head_base = (tileN & 1023) >> 6;
#pragma unroll
        for (int it = 0; it < 8; ++it) {
            int idx = it * 256 + tid;
            int tok = idx >> 4, cc = (idx & 15) * 8;
            int ar = tm + tok;
            int bb = ar / S;
            int nloc = seg_start + (ar % S);
            int hh2 = head_base + (cc >> 6), d = cc & 63;
            *(short8*)((short*)dst + ((size_t)(bb * HH + hh2) * NTOK + nloc) * HD + d) =
                *(const short8*)&buf[tok * 134 + cc];
        }
    } else {
        float bcol[4];
#pragma unroll
        for (int nb = 0; nb < 4; ++nb) bcol[nb] = bias[tileN + wn * 64 + nb * 16 + l15];
#pragma unroll
        for (int mb = 0; mb < 4; ++mb) {
#pragma unroll
            for (int r = 0; r < 4; ++r) {
                int tok = wm * 64 + mb * 16 + quad * 4 + r;
#pragma unroll
                for (int nb = 0; nb < 4; ++nb) {
                    int col = wn * 64 + nb * 16 + l15;
                    buf[col * 134 + tok] = bf16raw(acc[mb][nb][r] + bcol[nb]);
                }
            }
        }
        __syncthreads();
#pragma unroll
        for (int it = 0; it < 8; ++it) {
            int idx = it * 256 + tid;
            int row = idx >> 4;
            int tc = (idx & 15) * 8;
            int vcol = (tileN - 2048) + row;
            int h = vcol >> 6, d = vcol & 63;
            int ar = tm + tc;
            int bb = ar / S;
            int nloc = seg_start + (ar % S);
            short8 val = *(const short8*)&buf[row * 134 + tc];
            *(short8*)((short*)Vt + ((size_t)(bb * HH + h) * HD + d) * NTOK + nloc) = val;
        }
    }
}

// ---------------- proj GEMM 64Mx128N + FUSED split-K combine ----------------
// Per block the 64-row M-tile lies inside ONE attention qb-block (b, qb, nch
// uniform). K-step t covers exactly head t's 64 dims. Direct region (qb<=5):
// stage A from O via global_load_lds. Combined region: reg-load Opart partials,
// sum, scale by 1/sum(lpart), cvt bf16, ds_write into the same swizzled layout.
__global__ __launch_bounds__(256) void gemm_proj(
    const __hip_bfloat16* __restrict__ A,     // O (direct region valid)
    const __hip_bfloat16* __restrict__ Wb,    // (3, CC, CC)
    const float* __restrict__ biasb,          // (3, CC)
    const float* __restrict__ Opart,          // [32*17*3][128*64]
    const float* __restrict__ lpart,          // [32*17*3][128]
    float* __restrict__ Cout)
{
    // 48KB: buffer b at b*12288 shorts: [As 4096 | Bs 8192]
    __shared__ short lds[24576];

    int tid = threadIdx.x;
    int lane = tid & 63, w = tid >> 6;
    int l15 = lane & 15, quad = lane >> 4;
    int wm = w >> 1, wn = w & 1;
    int r7 = l15 & 7;

    int y = blockIdx.y;
    int seg, tm;
    if (y < 32)      { seg = 1; tm = y * 64; }
    else if (y < 64) { seg = 2; tm = (y - 32) * 64; }
    else             { seg = 0; tm = (y - 64) * 64; }
    int S = (seg == 0) ? 64 : 1024;
    int seg_start = (seg == 0) ? 0 : (seg == 1 ? NT : NT + NC);
    const short* W = (const short*)Wb + (size_t)seg * CC * CC;
    const float* bias = biasb + (size_t)seg * CC;
    int tileN = blockIdx.x * 128;

    // block-uniform attention-combine geometry
    int b_blk = tm / S;                       // uniform across the 64 rows
    int tok0 = seg_start + (tm % S);          // first token of this M-tile
    int qb_blk = tok0 >> 7;
    int nt = 2 * qb_blk + 2; if (nt > 33) nt = 33;
    int nch = (nt + 11) / 12;
    bool direct = (nt <= 12);

    // per-thread staging assignment (2 slots)
    const short* aptr[2];
    int rowj[2], uj[2];
#pragma unroll
    for (int j = 0; j < 2; ++j) {
        int c = j * 256 + tid;
        int row = c >> 3, u = (c & 7) ^ (row & 7);
        rowj[j] = row; uj[j] = u;
        int ar = tm + row;
        int arow = (ar / S) * NTOK + seg_start + (ar % S);
        aptr[j] = (const short*)A + (size_t)arow * CC + u * 8;
    }
    const short* bptr[4];
#pragma unroll
    for (int j = 0; j < 4; ++j) {
        int c = j * 256 + tid;
        int row = c >> 3, u = (c & 7) ^ (row & 7);
        bptr[j] = W + (size_t)(tileN + row) * CC + u * 8;
    }

    // combined-region reg-stage of head h into LDS buffer `dst`
    auto stage_comb = [&](int h, short* dst) {
        int pb = ((b_blk * HH + h) * 17 + qb_blk) * 3;
#pragma unroll
        for (int j = 0; j < 2; ++j) {
            int trow = (tok0 & 127) + rowj[j];
            float ls = 0.f;
            float4v v0 = {0.f, 0.f, 0.f, 0.f}, v1 = {0.f, 0.f, 0.f, 0.f};
            for (int cc = 0; cc < nch; ++cc) {
                ls += lpart[(size_t)(pb + cc) * 128 + trow];
                const float* op = Opart + (size_t)(pb + cc) * 8192 + trow * 64 + uj[j] * 8;
                float4v a0 = *(const float4v*)op;
                float4v a1 = *(const float4v*)(op + 4);
                v0.x += a0.x; v0.y += a0.y; v0.z += a0.z; v0.w += a0.w;
                v1.x += a1.x; v1.y += a1.y; v1.z += a1.z; v1.w += a1.w;
            }
            float inv = 1.0f / ls;
            short8 o;
            o[0] = bf16raw(v0.x * inv); o[1] = bf16raw(v0.y * inv);
            o[2] = bf16raw(v0.z * inv); o[3] = bf16raw(v0.w * inv);
            o[4] = bf16raw(v1.x * inv); o[5] = bf16raw(v1.y * inv);
            o[6] = bf16raw(v1.z * inv); o[7] = bf16raw(v1.w * inv);
            *(short8*)(dst + (j * 256 + tid) * 8) = o;
        }
    };

    f32x4 zero = {0.f, 0.f, 0.f, 0.f};
    f32x4 acc[2][4];
#pragma unroll
    for (int mb = 0; mb < 2; ++mb)
#pragma unroll
        for (int nb = 0; nb < 4; ++nb) acc[mb][nb] = zero;

    // prologue: stage tile 0 (head 0) into buffer 0
    if (direct) {
#pragma unroll
        for (int j = 0; j < 2; ++j)
            GL_LDS(aptr[j], lds + (j * 256 + tid) * 8);
    } else {
        stage_comb(0, lds);
    }
#pragma unroll
    for (int j = 0; j < 4; ++j)
        GL_LDS(bptr[j], lds + 4096 + (j * 256 + tid) * 8);
    __syncthreads();

    for (int t = 0; t < 16; ++t) {
        short* As = lds + (t & 1) * 12288;
        short* Bs = As + 4096;
        short* An = lds + ((t + 1) & 1) * 12288;
        if (t < 15) {
            int k0 = (t + 1) * 64;
            if (direct) {
#pragma unroll
                for (int j = 0; j < 2; ++j)
                    GL_LDS(aptr[j] + k0, An + (j * 256 + tid) * 8);
            } else {
                stage_comb(t + 1, An);
            }
#pragma unroll
            for (int j = 0; j < 4; ++j)
                GL_LDS(bptr[j] + k0, An + 4096 + (j * 256 + tid) * 8);
        }

#pragma unroll
        for (int s = 0; s < 2; ++s) {
            int sx = ((s * 4 + quad) ^ r7) * 8;
            short8 af[2], bf[4];
#pragma unroll
            for (int mb = 0; mb < 2; ++mb)
                af[mb] = *(const short8*)&As[(wm * 32 + mb * 16 + l15) * 64 + sx];
#pragma unroll
            for (int nb = 0; nb < 4; ++nb)
                bf[nb] = *(const short8*)&Bs[(wn * 64 + nb * 16 + l15) * 64 + sx];
#pragma unroll
            for (int mb = 0; mb < 2; ++mb)
#pragma unroll
                for (int nb = 0; nb < 4; ++nb)
                    acc[mb][nb] = __builtin_amdgcn_mfma_f32_16x16x32_bf16(af[mb], bf[nb], acc[mb][nb], 0, 0, 0);
        }
        __syncthreads();
    }

#pragma unroll
    for (int mb = 0; mb < 2; ++mb) {
#pragma unroll
        for (int r = 0; r < 4; ++r) {
            int ar = tm + wm * 32 + mb * 16 + quad * 4 + r;
            int crow = (ar / S) * NTOK + seg_start + (ar % S);
            float* cp = Cout + (size_t)crow * CC + tileN;
#pragma unroll
            for (int nb = 0; nb < 4; ++nb) {
                int col = wn * 64 + nb * 16 + l15;
                cp[col] = acc[mb][nb][r] + bias[tileN + col];
            }
        }
    }
}

// ---------------- split-K MFMA flash attention, 2-phase K/V dbuf ----------------
// exp2 softmax (Q pre-scaled by 0.125*log2e); interior-tile mask elision;
// setprio around MFMA clusters.
__global__ __launch_bounds__(512) void attn_part(
    const __hip_bfloat16* __restrict__ Q,
    const __hip_bfloat16* __restrict__ Kg,
    const __hip_bfloat16* __restrict__ Vt,
    __hip_bfloat16* __restrict__ O,
    float* __restrict__ Opart,        // [32*17*3][128*64]
    float* __restrict__ lpart)        // [32*17*3][128]
{
    __shared__ short Ks[2][4096];
    __shared__ short Vs[2][4096];
    __shared__ short Ps[8][16 * 72];

    int tid = threadIdx.x;
    int lane = tid & 63, w = tid >> 6;
    int quad = lane >> 4, l15 = lane & 15;
    int r7 = l15 & 7;
    int bh = blockIdx.y, b = bh >> 4, h = bh & 15;

    int e = blockIdx.x;
    int qb = QB_tab[e], c = CH_tab[e];
    int q0 = qb * 128;
    int nt = 2 * qb + 2; if (nt > 33) nt = 33;
    int t0 = c * 12, t1 = t0 + 12; if (t1 > nt) t1 = nt;
    bool direct = (nt <= 12);

    size_t base = (size_t)bh * NTOK * HD;

    int qrow = q0 + w * 16 + l15;
    int qr_c = qrow < NTOK ? qrow : NTOK - 1;
    short8 qf0 = *(const short8*)((const short*)Q + base + (size_t)qr_c * HD + quad * 8);
    short8 qf1 = *(const short8*)((const short*)Q + base + (size_t)qr_c * HD + 32 + quad * 8);

    int srow = tid >> 3;
    int su = (tid & 7) ^ (srow & 7);
    const short* kptr = (const short*)Kg + base + (size_t)srow * HD + su * 8;
    const short* vptr = (const short*)Vt + base + (size_t)srow * NTOK + su * 8;
    int c8 = tid * 8;

    f32x4 zero = {0.f, 0.f, 0.f, 0.f};
    f32x4 oacc[4] = {zero, zero, zero, zero};
    float l[4] = {0.f, 0.f, 0.f, 0.f};

    int qmin_w = q0 + w * 16;
    int qmax_w = qmin_w + 15;
    int sx0 = (quad ^ r7) * 8;
    int sx1 = ((4 + quad) ^ r7) * 8;

    // prologue: stage tile t0 into buffer 0
    GL_LDS(kptr + (size_t)(t0 * 64) * HD, Ks[0] + c8);
    GL_LDS(vptr + t0 * 64, Vs[0] + c8);
    __syncthreads();

    int cur = 0;
    for (int t = t0; t < t1; ++t) {
        if (t + 1 < t1) {   // prefetch next K/V tile
            GL_LDS(kptr + (size_t)((t + 1) * 64) * HD, Ks[cur ^ 1] + c8);
            GL_LDS(vptr + (t + 1) * 64, Vs[cur ^ 1] + c8);
        }

        if (t * 64 <= qmax_w) {
            f32x4 s[4];
            __builtin_amdgcn_s_setprio(1);
#pragma unroll
            for (int kb = 0; kb < 4; ++kb) {
                int krow = (kb * 16 + l15) * 64;
                short8 kf0 = *(const short8*)&Ks[cur][krow + sx0];
                short8 kf1 = *(const short8*)&Ks[cur][krow + sx1];
                f32x4 z = zero;
                z = __builtin_amdgcn_mfma_f32_16x16x32_bf16(qf0, kf0, z, 0, 0, 0);
                z = __builtin_amdgcn_mfma_f32_16x16x32_bf16(qf1, kf1, z, 0, 0, 0);
                s[kb] = z;
            }
            __builtin_amdgcn_s_setprio(0);

            if (t * 64 + 63 <= qmin_w) {
                // interior tile: fully causal for every row of this wave — no mask
#pragma unroll
                for (int r = 0; r < 4; ++r)
#pragma unroll
                    for (int kb = 0; kb < 4; ++kb) {
                        float p = __builtin_amdgcn_exp2f(s[kb][r]);
                        Ps[w][(quad * 4 + r) * 72 + kb * 16 + l15] = bf16raw(p);
                        l[r] += p;
                    }
            } else {
#pragma unroll
                for (int r = 0; r < 4; ++r) {
                    int qg = q0 + w * 16 + quad * 4 + r;
#pragma unroll
                    for (int kb = 0; kb < 4; ++kb) {
                        int kgk = t * 64 + kb * 16 + l15;
                        float p = (kgk <= qg) ? __builtin_amdgcn_exp2f(s[kb][r]) : 0.f;
                        Ps[w][(quad * 4 + r) * 72 + kb * 16 + l15] = bf16raw(p);
                        l[r] += p;
                    }
                }
            }

            __builtin_amdgcn_wave_barrier();

            __builtin_amdgcn_s_setprio(1);
#pragma unroll
            for (int sl = 0; sl < 2; ++sl) {
                short8 pf = *(const short8*)&Ps[w][l15 * 72 + sl * 32 + quad * 8];
                int vsx = ((sl * 4 + quad) ^ r7) * 8;
#pragma unroll
                for (int db = 0; db < 4; ++db) {
                    short8 vf = *(const short8*)&Vs[cur][(db * 16 + l15) * 64 + vsx];
                    oacc[db] = __builtin_amdgcn_mfma_f32_16x16x32_bf16(pf, vf, oacc[db], 0, 0, 0);
                }
            }
            __builtin_amdgcn_s_setprio(0);
        }

        __syncthreads();   // drains prefetch, frees Ks/Vs[cur]
        cur ^= 1;
    }

#pragma unroll
    for (int r = 0; r < 4; ++r) {
#pragma unroll
        for (int off = 8; off >= 1; off >>= 1) l[r] += __shfl_xor(l[r], off);
    }

    if (direct) {
#pragma unroll
        for (int r = 0; r < 4; ++r) {
            int qg = q0 + w * 16 + quad * 4 + r;
            float inv_l = 1.0f / l[r];
#pragma unroll
            for (int db = 0; db < 4; ++db) {
                O[(size_t)(b * NTOK + qg) * CC + h * HD + db * 16 + l15] =
                    __float2bfloat16(oacc[db][r] * inv_l);
            }
        }
    } else {
        int pidx = (bh * 17 + qb) * 3 + c;
        float* op = Opart + (size_t)pidx * (128 * 64);
#pragma unroll
        for (int r = 0; r < 4; ++r) {
            int q = w * 16 + quad * 4 + r;
#pragma unroll
            for (int db = 0; db < 4; ++db)
                op[q * 64 + db * 16 + l15] = oacc[db][r];
            if (l15 == 0) lpart[pidx * 128 + q] = l[r];
        }
    }
}

// ---------------- launch ----------------
extern "C" void kernel_launch(void* const* d_in, const int* in_sizes, int n_in,
                              void* d_out, int out_size, void* d_ws, size_t ws_size,
                              hipStream_t stream) {
    const float* x      = (const float*)d_in[0];
    const float* qkv_w  = (const float*)d_in[7];
    const float* qkv_b  = (const float*)d_in[8];
    const float* qn_w   = (const float*)d_in[9];
    const float* qn_b   = (const float*)d_in[10];
    const float* kn_w   = (const float*)d_in[11];
    const float* kn_b   = (const float*)d_in[12];
    const float* proj_w = (const float*)d_in[13];
    const float* proj_b = (const float*)d_in[14];
    float* out = (float*)d_out;

    const size_t n_x    = (size_t)BB * NTOK * CC;
    const size_t n_qkvw = (size_t)3 * K3 * CC;
    const size_t n_prjw = (size_t)3 * CC * CC;
    const size_t n_part = (size_t)32 * 17 * 3;

    __hip_bfloat16* x_bf    = (__hip_bfloat16*)d_ws;
    __hip_bfloat16* qkvw_bf = x_bf + n_x;
    __hip_bfloat16* prjw_bf = qkvw_bf + n_qkvw;
    __hip_bfloat16* Qbf  = prjw_bf + n_prjw;
    __hip_bfloat16* Kbf  = Qbf + n_x;
    __hip_bfloat16* Vtbf = Kbf + n_x;
    float* Opart = (float*)(Vtbf + n_x);
    float* lpart = Opart + n_part * (128 * 64);
    __hip_bfloat16* attn_bf = x_bf;   // reuse: x_bf dead after gemm_qkv

    cast_all<<<1024, 256, 0, stream>>>(x, qkv_w, proj_w, x_bf, qkvw_bf, prjw_bf,
                                       (int)(n_x / 4), (int)(n_qkvw / 4), (int)(n_prjw / 4));

    gemm_qkv<<<dim3(K3 / 128, 33), 256, 0, stream>>>(
        x_bf, qkvw_bf, qkv_b,
        qn_w, qn_b, kn_w, kn_b, Qbf, Kbf, Vtbf);

    attn_part<<<dim3(33, BB * HH), 512, 0, stream>>>(Qbf, Kbf, Vtbf, attn_bf, Opart, lpart);

    gemm_proj<<<dim3(CC / 128, 66), 256, 0, stream>>>(attn_bf, prjw_bf, proj_b,
                                                      Opart, lpart, out);
}

// Round 9
// 268.789 us; speedup vs baseline: 1.0237x; 1.0237x over previous
//
#include <hip/hip_runtime.h>
#include <hip/hip_bf16.h>

// ---- problem constants ----
#define BB   2
#define NT   64
#define NC   1024
#define NN   1024
#define NTOK (NT + NC + NN)   // 2112
#define CC   1024
#define HH   16
#define HD   64
#define K3   (3 * CC)
#define EPSV 1e-5f

typedef __attribute__((ext_vector_type(8))) short short8;
typedef __attribute__((ext_vector_type(4))) float f32x4;
typedef __attribute__((ext_vector_type(4))) float float4v;

__device__ __forceinline__ short bf16raw(float x) {
    __hip_bfloat16 h = __float2bfloat16(x);
    return *(short*)&h;
}

#define GL_LDS(gptr, lptr) \
    __builtin_amdgcn_global_load_lds( \
        (const __attribute__((address_space(1))) void*)(gptr), \
        (__attribute__((address_space(3))) void*)(lptr), 16, 0, 0)

// counted-vmcnt barrier pair (gemm_qkv only — pays when loads/step is large)
#define WAIT_VM(N) asm volatile("s_waitcnt vmcnt(" #N ")" ::: "memory")
#define BARRIER_FENCED() do { __builtin_amdgcn_s_barrier(); \
                              asm volatile("" ::: "memory"); } while (0)
#define FENCE_BARRIER()  do { asm volatile("" ::: "memory"); \
                              __builtin_amdgcn_s_barrier(); } while (0)

// split-K chunk tables (file-scope __constant__)
__constant__ signed char QB_tab[33] =
    {16,16,16,15,15,15,14,14,14,13,13,13,12,12,12,11,11,10,10,9,9,8,8,7,7,6,6,5,4,3,2,1,0};
__constant__ signed char CH_tab[33] =
    { 0, 1, 2, 0, 1, 2, 0, 1, 2, 0, 1, 2, 0, 1, 2, 0, 1, 0, 1,0,1,0,1,0,1,0,1,0,0,0,0,0,0};

// ---------------- merged cast fp32 -> bf16 (vectorized x4) ----------------
__global__ __launch_bounds__(256) void cast_all(
    const float* __restrict__ s0, const float* __restrict__ s1, const float* __restrict__ s2,
    __hip_bfloat16* __restrict__ d0, __hip_bfloat16* __restrict__ d1, __hip_bfloat16* __restrict__ d2,
    int n0, int n1, int n2)   // counts in float4 units
{
    int i = blockIdx.x * 256 + threadIdx.x;
    int stride = gridDim.x * 256;
    int ntot = n0 + n1 + n2;
    for (; i < ntot; i += stride) {
        const float* sp; short* dp; int j;
        if (i < n0)            { sp = s0; dp = (short*)d0; j = i; }
        else if (i < n0 + n1)  { sp = s1; dp = (short*)d1; j = i - n0; }
        else                   { sp = s2; dp = (short*)d2; j = i - n0 - n1; }
        float4v v = *(const float4v*)(sp + (size_t)j * 4);
        short4 o;
        o.x = bf16raw(v.x); o.y = bf16raw(v.y); o.z = bf16raw(v.z); o.w = bf16raw(v.w);
        *(short4*)(dp + (size_t)j * 4) = o;
    }
}

// ---------------- QKV GEMM 128x128, BK=64 swizzled, counted-vmcnt dbuf ----
// + fused LN/RoPE/V-transpose epilogue
// NOTE: Q is scaled by 0.125 * log2(e) so attention can use exp2 directly.
__global__ __launch_bounds__(256) void gemm_qkv(
    const __hip_bfloat16* __restrict__ A,     // (BB*NTOK, CC) bf16
    const __hip_bfloat16* __restrict__ Wb,    // (3, K3, CC) bf16
    const float* __restrict__ biasb,          // (3, K3)
    const float* __restrict__ qn_w, const float* __restrict__ qn_b,
    const float* __restrict__ kn_w, const float* __restrict__ kn_b,
    __hip_bfloat16* __restrict__ Q,           // (BB*HH, NTOK, HD)
    __hip_bfloat16* __restrict__ Kg,
    __hip_bfloat16* __restrict__ Vt)          // (BB*HH, HD, NTOK)
{
    // 64KB: buffer b at b*16384 shorts: [As 8192 | Bs 8192]
    __shared__ short lds[32768];
    short* buf = lds;   // epilogue scratch (128*134 = 17152 shorts, overlaid)

    int tid = threadIdx.x;
    int lane = tid & 63, w = tid >> 6;
    int l15 = lane & 15, quad = lane >> 4;
    int wm = w >> 1, wn = w & 1;
    int r7 = l15 & 7;

    int y = blockIdx.y;
    int seg, tm;
    if (y < 16)      { seg = 1; tm = y * 128; }
    else if (y < 32) { seg = 2; tm = (y - 16) * 128; }
    else             { seg = 0; tm = 0; }
    int S = (seg == 0) ? 64 : 1024;
    int seg_start = (seg == 0) ? 0 : (seg == 1 ? NT : NT + NC);
    const short* W = (const short*)Wb + (size_t)seg * K3 * CC;
    const float* bias = biasb + (size_t)seg * K3;
    int tileN = blockIdx.x * 128;

    const short* aptr[4];
    const short* bptr[4];
#pragma unroll
    for (int j = 0; j < 4; ++j) {
        int c = j * 256 + tid;
        int row = c >> 3, u = (c & 7) ^ (row & 7);
        int ar = tm + row;
        int arow = (ar / S) * NTOK + seg_start + (ar % S);
        aptr[j] = (const short*)A + (size_t)arow * CC + u * 8;
        bptr[j] = W + (size_t)(tileN + row) * CC + u * 8;
    }

    f32x4 zero = {0.f, 0.f, 0.f, 0.f};
    f32x4 acc[4][4];
#pragma unroll
    for (int mb = 0; mb < 4; ++mb)
#pragma unroll
        for (int nb = 0; nb < 4; ++nb) acc[mb][nb] = zero;

    // prologue: stage K-tile 0 into buffer 0; full drain resets compiler vm-model
#pragma unroll
    for (int j = 0; j < 4; ++j) {
        int c8 = (j * 256 + tid) * 8;
        GL_LDS(aptr[j], lds + c8);
        GL_LDS(bptr[j], lds + 8192 + c8);
    }
    __syncthreads();

    for (int t = 0; t < 16; ++t) {
        short* As = lds + (t & 1) * 16384;
        short* Bs = As + 8192;
        if (t < 15) {   // prefetch tile t+1 into the other buffer; stays in flight
            short* An = lds + ((t + 1) & 1) * 16384;
            int k0 = (t + 1) * 64;
#pragma unroll
            for (int j = 0; j < 4; ++j) {
                int c8 = (j * 256 + tid) * 8;
                GL_LDS(aptr[j] + k0, An + c8);
                GL_LDS(bptr[j] + k0, An + 8192 + c8);
            }
            WAIT_VM(8);       // tile-t loads (oldest 8) landed; t+1's 8 in flight
        } else {
            WAIT_VM(0);
        }
        BARRIER_FENCED();     // all waves: tile t visible

#pragma unroll
        for (int s = 0; s < 2; ++s) {
            int sx = ((s * 4 + quad) ^ r7) * 8;
            short8 af[4], bf[4];
#pragma unroll
            for (int mb = 0; mb < 4; ++mb)
                af[mb] = *(const short8*)&As[(wm * 64 + mb * 16 + l15) * 64 + sx];
#pragma unroll
            for (int nb = 0; nb < 4; ++nb)
                bf[nb] = *(const short8*)&Bs[(wn * 64 + nb * 16 + l15) * 64 + sx];
#pragma unroll
            for (int mb = 0; mb < 4; ++mb)
#pragma unroll
                for (int nb = 0; nb < 4; ++nb)
                    acc[mb][nb] = __builtin_amdgcn_mfma_f32_16x16x32_bf16(af[mb], bf[nb], acc[mb][nb], 0, 0, 0);
        }
        FENCE_BARRIER();      // all waves done reading buf[t&1] before overwrite
    }

    int sect = tileN >> 10;                    // 0=Q, 1=K, 2=V

    if (sect < 2) {
        const float* nw = (sect == 0 ? qn_w : kn_w) + seg * HD;
        const float* nbv = (sect == 0 ? qn_b : kn_b) + seg * HD;
        float lw[4], lb[4], bcol[4];
#pragma unroll
        for (int nb = 0; nb < 4; ++nb) {
            lw[nb] = nw[nb * 16 + l15];
            lb[nb] = nbv[nb * 16 + l15];
            bcol[nb] = bias[tileN + wn * 64 + nb * 16 + l15];
        }
        // 0.125 * log2(e): attention uses exp2
        float qscale = (sect == 0) ? 0.18033688011112042f : 1.0f;

        float invf0 = expf(-9.210340371976184f * (float)l15 * (1.0f / 32.0f));
        float invf1 = expf(-9.210340371976184f * (float)(16 + l15) * (1.0f / 32.0f));
        float cd0, sd0, cd1, sd1;
        sincosf(invf0, &sd0, &cd0);   // unit-step rotation
        sincosf(invf1, &sd1, &cd1);

#pragma unroll
        for (int mb = 0; mb < 4; ++mb) {
            // pos for r=0 of this (mb, quad) group; r=0..3 tokens are consecutive
            int tok0 = wm * 64 + mb * 16 + quad * 4;
            int ar0 = tm + tok0;
            int nloc0 = ar0 % S;                           // local within segment
            int pos0 = (seg == 0) ? nloc0 : (seg_start + nloc0 - NT);
            float c0, s0, c1, s1v;
            sincosf((float)pos0 * invf0, &s0, &c0);
            sincosf((float)pos0 * invf1, &s1v, &c1);

#pragma unroll
            for (int r = 0; r < 4; ++r) {
                int tok = tok0 + r;
                float v[4];
#pragma unroll
                for (int nb = 0; nb < 4; ++nb) v[nb] = acc[mb][nb][r] + bcol[nb];

                // one-pass LN: reduce (sum, sumsq) together
                float t1 = v[0] + v[1] + v[2] + v[3];
                float t2 = v[0] * v[0] + v[1] * v[1] + v[2] * v[2] + v[3] * v[3];
#pragma unroll
                for (int off = 8; off >= 1; off >>= 1) {
                    t1 += __shfl_xor(t1, off);
                    t2 += __shfl_xor(t2, off);
                }
                float mu = t1 * (1.0f / 64.0f);
                float var = t2 * (1.0f / 64.0f) - mu * mu;
                float rstd = rsqrtf(var + EPSV);
#pragma unroll
                for (int nb = 0; nb < 4; ++nb) v[nb] = (v[nb] - mu) * rstd * lw[nb] + lb[nb];

                short* bp = &buf[tok * 134 + wn * 64];
                bp[0 * 16 + l15] = bf16raw((v[0] * c0 - v[2] * s0) * qscale);
                bp[1 * 16 + l15] = bf16raw((v[1] * c1 - v[3] * s1v) * qscale);
                bp[2 * 16 + l15] = bf16raw((v[2] * c0 + v[0] * s0) * qscale);
                bp[3 * 16 + l15] = bf16raw((v[3] * c1 + v[1] * s1v) * qscale);

                // advance rotation to next consecutive position
                float nc0 = c0 * cd0 - s0 * sd0, ns0 = s0 * cd0 + c0 * sd0;
                float nc1 = c1 * cd1 - s1v * sd1, ns1 = s1v * cd1 + c1 * sd1;
                c0 = nc0; s0 = ns0; c1 = nc1; s1v = ns1;
            }
        }
        __syncthreads();
        __hip_bfloat16* dst = (sect == 0) ? Q : Kg;
        int head_base = (tileN & 1023) >> 6;
#pragma unroll
        for (int it = 0; it < 8; ++it) {
            int idx = it * 256 + tid;
            int tok = idx >> 4, cc = (idx & 15) * 8;
            int ar = tm + tok;
            int bb = ar / S;
            int nloc = seg_start + (ar % S);
            int hh2 = head_base + (cc >> 6), d = cc & 63;
            *(short8*)((short*)dst + ((size_t)(bb * HH + hh2) * NTOK + nloc) * HD + d) =
                *(const short8*)&buf[tok * 134 + cc];
        }
    } else {
        float bcol[4];
#pragma unroll
        for (int nb = 0; nb < 4; ++nb) bcol[nb] = bias[tileN + wn * 64 + nb * 16 + l15];
#pragma unroll
        for (int mb = 0; mb < 4; ++mb) {
#pragma unroll
            for (int r = 0; r < 4; ++r) {
                int tok = wm * 64 + mb * 16 + quad * 4 + r;
#pragma unroll
                for (int nb = 0; nb < 4; ++nb) {
                    int col = wn * 64 + nb * 16 + l15;
                    buf[col * 134 + tok] = bf16raw(acc[mb][nb][r] + bcol[nb]);
                }
            }
        }
        __syncthreads();
#pragma unroll
        for (int it = 0; it < 8; ++it) {
            int idx = it * 256 + tid;
            int row = idx >> 4;
            int tc = (idx & 15) * 8;
            int vcol = (tileN - 2048) + row;
            int h = vcol >> 6, d = vcol & 63;
            int ar = tm + tc;
            int bb = ar / S;
            int nloc = seg_start + (ar % S);
            short8 val = *(const short8*)&buf[row * 134 + tc];
            *(short8*)((short*)Vt + ((size_t)(bb * HH + h) * HD + d) * NTOK + nloc) = val;
        }
    }
}

// ---------------- proj GEMM: 64Mx128N tile, BK=64 swizzled, 2-phase dbuf ----
__global__ __launch_bounds__(256) void gemm_proj(
    const __hip_bfloat16* __restrict__ A,
    const __hip_bfloat16* __restrict__ Wb,    // (3, CC, CC)
    const float* __restrict__ biasb,          // (3, CC)
    float* __restrict__ Cout)
{
    // 48KB: buffer b at b*12288 shorts: [As 4096 | Bs 8192]
    __shared__ short lds[24576];

    int tid = threadIdx.x;
    int lane = tid & 63, w = tid >> 6;
    int l15 = lane & 15, quad = lane >> 4;
    int wm = w >> 1, wn = w & 1;
    int r7 = l15 & 7;

    int y = blockIdx.y;
    int seg, tm;
    if (y < 32)      { seg = 1; tm = y * 64; }
    else if (y < 64) { seg = 2; tm = (y - 32) * 64; }
    else             { seg = 0; tm = (y - 64) * 64; }
    int S = (seg == 0) ? 64 : 1024;
    int seg_start = (seg == 0) ? 0 : (seg == 1 ? NT : NT + NC);
    const short* W = (const short*)Wb + (size_t)seg * CC * CC;
    const float* bias = biasb + (size_t)seg * CC;
    int tileN = blockIdx.x * 128;

    const short* aptr[2];
    const short* bptr[4];
#pragma unroll
    for (int j = 0; j < 2; ++j) {
        int c = j * 256 + tid;
        int row = c >> 3, u = (c & 7) ^ (row & 7);
        int ar = tm + row;
        int arow = (ar / S) * NTOK + seg_start + (ar % S);
        aptr[j] = (const short*)A + (size_t)arow * CC + u * 8;
    }
#pragma unroll
    for (int j = 0; j < 4; ++j) {
        int c = j * 256 + tid;
        int row = c >> 3, u = (c & 7) ^ (row & 7);
        bptr[j] = W + (size_t)(tileN + row) * CC + u * 8;
    }

    f32x4 zero = {0.f, 0.f, 0.f, 0.f};
    f32x4 acc[2][4];
#pragma unroll
    for (int mb = 0; mb < 2; ++mb)
#pragma unroll
        for (int nb = 0; nb < 4; ++nb) acc[mb][nb] = zero;

    // prologue: stage tile 0 into buffer 0
#pragma unroll
    for (int j = 0; j < 2; ++j)
        GL_LDS(aptr[j], lds + (j * 256 + tid) * 8);
#pragma unroll
    for (int j = 0; j < 4; ++j)
        GL_LDS(bptr[j], lds + 4096 + (j * 256 + tid) * 8);
    __syncthreads();

    int cur = 0;
    for (int k0 = 64; k0 <= CC; k0 += 64) {
        short* As = lds + cur * 12288;
        short* Bs = As + 4096;
        if (k0 < CC) {
            short* An = lds + (cur ^ 1) * 12288;
#pragma unroll
            for (int j = 0; j < 2; ++j)
                GL_LDS(aptr[j] + k0, An + (j * 256 + tid) * 8);
#pragma unroll
            for (int j = 0; j < 4; ++j)
                GL_LDS(bptr[j] + k0, An + 4096 + (j * 256 + tid) * 8);
        }

#pragma unroll
        for (int s = 0; s < 2; ++s) {
            int sx = ((s * 4 + quad) ^ r7) * 8;
            short8 af[2], bf[4];
#pragma unroll
            for (int mb = 0; mb < 2; ++mb)
                af[mb] = *(const short8*)&As[(wm * 32 + mb * 16 + l15) * 64 + sx];
#pragma unroll
            for (int nb = 0; nb < 4; ++nb)
                bf[nb] = *(const short8*)&Bs[(wn * 64 + nb * 16 + l15) * 64 + sx];
#pragma unroll
            for (int mb = 0; mb < 2; ++mb)
#pragma unroll
                for (int nb = 0; nb < 4; ++nb)
                    acc[mb][nb] = __builtin_amdgcn_mfma_f32_16x16x32_bf16(af[mb], bf[nb], acc[mb][nb], 0, 0, 0);
        }
        __syncthreads();
        cur ^= 1;
    }

#pragma unroll
    for (int mb = 0; mb < 2; ++mb) {
#pragma unroll
        for (int r = 0; r < 4; ++r) {
            int ar = tm + wm * 32 + mb * 16 + quad * 4 + r;
            int crow = (ar / S) * NTOK + seg_start + (ar % S);
            float* cp = Cout + (size_t)crow * CC + tileN;
#pragma unroll
            for (int nb = 0; nb < 4; ++nb) {
                int col = wn * 64 + nb * 16 + l15;
                cp[col] = acc[mb][nb][r] + bias[tileN + col];
            }
        }
    }
}

// ---------------- split-K MFMA flash attention, 2-phase K/V dbuf ----------------
// exp2 softmax (Q pre-scaled by 0.125*log2e); interior-tile mask elision;
// setprio around MFMA clusters.
__global__ __launch_bounds__(512) void attn_part(
    const __hip_bfloat16* __restrict__ Q,
    const __hip_bfloat16* __restrict__ Kg,
    const __hip_bfloat16* __restrict__ Vt,
    __hip_bfloat16* __restrict__ O,
    float* __restrict__ Opart,        // [32*17*3][128*64]
    float* __restrict__ lpart)        // [32*17*3][128]
{
    __shared__ short Ks[2][4096];
    __shared__ short Vs[2][4096];
    __shared__ short Ps[8][16 * 72];

    int tid = threadIdx.x;
    int lane = tid & 63, w = tid >> 6;
    int quad = lane >> 4, l15 = lane & 15;
    int r7 = l15 & 7;
    int bh = blockIdx.y, b = bh >> 4, h = bh & 15;

    int e = blockIdx.x;
    int qb = QB_tab[e], c = CH_tab[e];
    int q0 = qb * 128;
    int nt = 2 * qb + 2; if (nt > 33) nt = 33;
    int t0 = c * 12, t1 = t0 + 12; if (t1 > nt) t1 = nt;
    bool direct = (nt <= 12);

    size_t base = (size_t)bh * NTOK * HD;

    int qrow = q0 + w * 16 + l15;
    int qr_c = qrow < NTOK ? qrow : NTOK - 1;
    short8 qf0 = *(const short8*)((const short*)Q + base + (size_t)qr_c * HD + quad * 8);
    short8 qf1 = *(const short8*)((const short*)Q + base + (size_t)qr_c * HD + 32 + quad * 8);

    int srow = tid >> 3;
    int su = (tid & 7) ^ (srow & 7);
    const short* kptr = (const short*)Kg + base + (size_t)srow * HD + su * 8;
    const short* vptr = (const short*)Vt + base + (size_t)srow * NTOK + su * 8;
    int c8 = tid * 8;

    f32x4 zero = {0.f, 0.f, 0.f, 0.f};
    f32x4 oacc[4] = {zero, zero, zero, zero};
    float l[4] = {0.f, 0.f, 0.f, 0.f};

    int qmin_w = q0 + w * 16;
    int qmax_w = qmin_w + 15;
    int sx0 = (quad ^ r7) * 8;
    int sx1 = ((4 + quad) ^ r7) * 8;

    // prologue: stage tile t0 into buffer 0
    GL_LDS(kptr + (size_t)(t0 * 64) * HD, Ks[0] + c8);
    GL_LDS(vptr + t0 * 64, Vs[0] + c8);
    __syncthreads();

    int cur = 0;
    for (int t = t0; t < t1; ++t) {
        if (t + 1 < t1) {   // prefetch next K/V tile
            GL_LDS(kptr + (size_t)((t + 1) * 64) * HD, Ks[cur ^ 1] + c8);
            GL_LDS(vptr + (t + 1) * 64, Vs[cur ^ 1] + c8);
        }

        if (t * 64 <= qmax_w) {
            f32x4 s[4];
            __builtin_amdgcn_s_setprio(1);
#pragma unroll
            for (int kb = 0; kb < 4; ++kb) {
                int krow = (kb * 16 + l15) * 64;
                short8 kf0 = *(const short8*)&Ks[cur][krow + sx0];
                short8 kf1 = *(const short8*)&Ks[cur][krow + sx1];
                f32x4 z = zero;
                z = __builtin_amdgcn_mfma_f32_16x16x32_bf16(qf0, kf0, z, 0, 0, 0);
                z = __builtin_amdgcn_mfma_f32_16x16x32_bf16(qf1, kf1, z, 0, 0, 0);
                s[kb] = z;
            }
            __builtin_amdgcn_s_setprio(0);

            if (t * 64 + 63 <= qmin_w) {
                // interior tile: fully causal for every row of this wave — no mask
#pragma unroll
                for (int r = 0; r < 4; ++r)
#pragma unroll
                    for (int kb = 0; kb < 4; ++kb) {
                        float p = __builtin_amdgcn_exp2f(s[kb][r]);
                        Ps[w][(quad * 4 + r) * 72 + kb * 16 + l15] = bf16raw(p);
                        l[r] += p;
                    }
            } else {
#pragma unroll
                for (int r = 0; r < 4; ++r) {
                    int qg = q0 + w * 16 + quad * 4 + r;
#pragma unroll
                    for (int kb = 0; kb < 4; ++kb) {
                        int kgk = t * 64 + kb * 16 + l15;
                        float p = (kgk <= qg) ? __builtin_amdgcn_exp2f(s[kb][r]) : 0.f;
                        Ps[w][(quad * 4 + r) * 72 + kb * 16 + l15] = bf16raw(p);
                        l[r] += p;
                    }
                }
            }

            __builtin_amdgcn_wave_barrier();

            __builtin_amdgcn_s_setprio(1);
#pragma unroll
            for (int sl = 0; sl < 2; ++sl) {
                short8 pf = *(const short8*)&Ps[w][l15 * 72 + sl * 32 + quad * 8];
                int vsx = ((sl * 4 + quad) ^ r7) * 8;
#pragma unroll
                for (int db = 0; db < 4; ++db) {
                    short8 vf = *(const short8*)&Vs[cur][(db * 16 + l15) * 64 + vsx];
                    oacc[db] = __builtin_amdgcn_mfma_f32_16x16x32_bf16(pf, vf, oacc[db], 0, 0, 0);
                }
            }
            __builtin_amdgcn_s_setprio(0);
        }

        __syncthreads();   // drains prefetch, frees Ks/Vs[cur]
        cur ^= 1;
    }

#pragma unroll
    for (int r = 0; r < 4; ++r) {
#pragma unroll
        for (int off = 8; off >= 1; off >>= 1) l[r] += __shfl_xor(l[r], off);
    }

    if (direct) {
#pragma unroll
        for (int r = 0; r < 4; ++r) {
            int qg = q0 + w * 16 + quad * 4 + r;
            float inv_l = 1.0f / l[r];
#pragma unroll
            for (int db = 0; db < 4; ++db) {
                O[(size_t)(b * NTOK + qg) * CC + h * HD + db * 16 + l15] =
                    __float2bfloat16(oacc[db][r] * inv_l);
            }
        }
    } else {
        int pidx = (bh * 17 + qb) * 3 + c;
        float* op = Opart + (size_t)pidx * (128 * 64);
#pragma unroll
        for (int r = 0; r < 4; ++r) {
            int q = w * 16 + quad * 4 + r;
#pragma unroll
            for (int db = 0; db < 4; ++db)
                op[q * 64 + db * 16 + l15] = oacc[db][r];
            if (l15 == 0) lpart[pidx * 128 + q] = l[r];
        }
    }
}

// ---------------- combine partials: sum + normalize + bf16 ----------------
__global__ __launch_bounds__(512) void attn_comb(
    const float* __restrict__ Opart, const float* __restrict__ lpart,
    __hip_bfloat16* __restrict__ O)
{
    __shared__ float ls[128];
    int tid = threadIdx.x;
    int qb = 6 + blockIdx.x;
    int bh = blockIdx.y, b = bh >> 4, h = bh & 15;
    int nt = 2 * qb + 2; if (nt > 33) nt = 33;
    int nch = (nt + 11) / 12;
    int q0 = qb * 128;
    int pbase = (bh * 17 + qb) * 3;

    if (tid < 128) {
        float s = 0.f;
        for (int cc = 0; cc < nch; ++cc) s += lpart[(pbase + cc) * 128 + tid];
        ls[tid] = 1.0f / s;
    }
    __syncthreads();

#pragma unroll
    for (int k = 0; k < 16; ++k) {
        int elem = k * 512 + tid;
        int q = elem >> 6, d = elem & 63;
        int qg = q0 + q;
        if (qg >= NTOK) continue;
        float s = 0.f;
        for (int cc = 0; cc < nch; ++cc)
            s += Opart[(size_t)(pbase + cc) * (128 * 64) + elem];
        O[(size_t)(b * NTOK + qg) * CC + h * HD + d] = __float2bfloat16(s * ls[q]);
    }
}

// ---------------- launch ----------------
extern "C" void kernel_launch(void* const* d_in, const int* in_sizes, int n_in,
                              void* d_out, int out_size, void* d_ws, size_t ws_size,
                              hipStream_t stream) {
    const float* x      = (const float*)d_in[0];
    const float* qkv_w  = (const float*)d_in[7];
    const float* qkv_b  = (const float*)d_in[8];
    const float* qn_w   = (const float*)d_in[9];
    const float* qn_b   = (const float*)d_in[10];
    const float* kn_w   = (const float*)d_in[11];
    const float* kn_b   = (const float*)d_in[12];
    const float* proj_w = (const float*)d_in[13];
    const float* proj_b = (const float*)d_in[14];
    float* out = (float*)d_out;

    const size_t n_x    = (size_t)BB * NTOK * CC;
    const size_t n_qkvw = (size_t)3 * K3 * CC;
    const size_t n_prjw = (size_t)3 * CC * CC;
    const size_t n_part = (size_t)32 * 17 * 3;

    __hip_bfloat16* x_bf    = (__hip_bfloat16*)d_ws;
    __hip_bfloat16* qkvw_bf = x_bf + n_x;
    __hip_bfloat16* prjw_bf = qkvw_bf + n_qkvw;
    __hip_bfloat16* Qbf  = prjw_bf + n_prjw;
    __hip_bfloat16* Kbf  = Qbf + n_x;
    __hip_bfloat16* Vtbf = Kbf + n_x;
    float* Opart = (float*)(Vtbf + n_x);
    float* lpart = Opart + n_part * (128 * 64);
    __hip_bfloat16* attn_bf = x_bf;   // reuse: x_bf dead after gemm_qkv

    cast_all<<<1024, 256, 0, stream>>>(x, qkv_w, proj_w, x_bf, qkvw_bf, prjw_bf,
                                       (int)(n_x / 4), (int)(n_qkvw / 4), (int)(n_prjw / 4));

    gemm_qkv<<<dim3(K3 / 128, 33), 256, 0, stream>>>(
        x_bf, qkvw_bf, qkv_b,
        qn_w, qn_b, kn_w, kn_b, Qbf, Kbf, Vtbf);

    attn_part<<<dim3(33, BB * HH), 512, 0, stream>>>(Qbf, Kbf, Vtbf, attn_bf, Opart, lpart);

    attn_comb<<<dim3(11, BB * HH), 512, 0, stream>>>(Opart, lpart, attn_bf);

    gemm_proj<<<dim3(CC / 128, 66), 256, 0, stream>>>(attn_bf, prjw_bf, proj_b, out);
}

// Round 10
// 258.451 us; speedup vs baseline: 1.0647x; 1.0400x over previous
//
#include <hip/hip_runtime.h>
#include <hip/hip_bf16.h>

// ---- problem constants ----
#define BB   2
#define NT   64
#define NC   1024
#define NN   1024
#define NTOK (NT + NC + NN)   // 2112
#define CC   1024
#define HH   16
#define HD   64
#define K3   (3 * CC)
#define EPSV 1e-5f

typedef __attribute__((ext_vector_type(8))) short short8;
typedef __attribute__((ext_vector_type(4))) float f32x4;
typedef __attribute__((ext_vector_type(4))) float float4v;

__device__ __forceinline__ short bf16raw(float x) {
    __hip_bfloat16 h = __float2bfloat16(x);
    return *(short*)&h;
}

#define GL_LDS(gptr, lptr) \
    __builtin_amdgcn_global_load_lds( \
        (const __attribute__((address_space(1))) void*)(gptr), \
        (__attribute__((address_space(3))) void*)(lptr), 16, 0, 0)

// split-K chunk tables (file-scope __constant__)
__constant__ signed char QB_tab[33] =
    {16,16,16,15,15,15,14,14,14,13,13,13,12,12,12,11,11,10,10,9,9,8,8,7,7,6,6,5,4,3,2,1,0};
__constant__ signed char CH_tab[33] =
    { 0, 1, 2, 0, 1, 2, 0, 1, 2, 0, 1, 2, 0, 1, 2, 0, 1, 0, 1,0,1,0,1,0,1,0,1,0,0,0,0,0,0};

// ---------------- merged cast fp32 -> bf16 (vectorized x4) ----------------
__global__ __launch_bounds__(256) void cast_all(
    const float* __restrict__ s0, const float* __restrict__ s1, const float* __restrict__ s2,
    __hip_bfloat16* __restrict__ d0, __hip_bfloat16* __restrict__ d1, __hip_bfloat16* __restrict__ d2,
    int n0, int n1, int n2)   // counts in float4 units
{
    int i = blockIdx.x * 256 + threadIdx.x;
    int stride = gridDim.x * 256;
    int ntot = n0 + n1 + n2;
    for (; i < ntot; i += stride) {
        const float* sp; short* dp; int j;
        if (i < n0)            { sp = s0; dp = (short*)d0; j = i; }
        else if (i < n0 + n1)  { sp = s1; dp = (short*)d1; j = i - n0; }
        else                   { sp = s2; dp = (short*)d2; j = i - n0 - n1; }
        float4v v = *(const float4v*)(sp + (size_t)j * 4);
        short4 o;
        o.x = bf16raw(v.x); o.y = bf16raw(v.y); o.z = bf16raw(v.z); o.w = bf16raw(v.w);
        *(short4*)(dp + (size_t)j * 4) = o;
    }
}

// ---------------- QKV GEMM 128x128, BK=64 swizzled, 2-phase dbuf pipeline ----
// + fused LN/RoPE/V-transpose epilogue
// NOTE: Q is scaled by 0.125 * log2(e) so attention can use exp2 directly.
__global__ __launch_bounds__(256) void gemm_qkv(
    const __hip_bfloat16* __restrict__ A,     // (BB*NTOK, CC) bf16
    const __hip_bfloat16* __restrict__ Wb,    // (3, K3, CC) bf16
    const float* __restrict__ biasb,          // (3, K3)
    const float* __restrict__ qn_w, const float* __restrict__ qn_b,
    const float* __restrict__ kn_w, const float* __restrict__ kn_b,
    __hip_bfloat16* __restrict__ Q,           // (BB*HH, NTOK, HD)
    __hip_bfloat16* __restrict__ Kg,
    __hip_bfloat16* __restrict__ Vt)          // (BB*HH, HD, NTOK)
{
    // 64KB: buffer b at b*16384 shorts: [As 8192 | Bs 8192]
    __shared__ short lds[32768];
    short* buf = lds;   // epilogue scratch (128*134 = 17152 shorts, overlaid)

    int tid = threadIdx.x;
    int lane = tid & 63, w = tid >> 6;
    int l15 = lane & 15, quad = lane >> 4;
    int wm = w >> 1, wn = w & 1;
    int r7 = l15 & 7;

    int y = blockIdx.y;
    int seg, tm;
    if (y < 16)      { seg = 1; tm = y * 128; }
    else if (y < 32) { seg = 2; tm = (y - 16) * 128; }
    else             { seg = 0; tm = 0; }
    int S = (seg == 0) ? 64 : 1024;
    int seg_start = (seg == 0) ? 0 : (seg == 1 ? NT : NT + NC);
    const short* W = (const short*)Wb + (size_t)seg * K3 * CC;
    const float* bias = biasb + (size_t)seg * K3;
    int tileN = blockIdx.x * 128;

    const short* aptr[4];
    const short* bptr[4];
#pragma unroll
    for (int j = 0; j < 4; ++j) {
        int c = j * 256 + tid;
        int row = c >> 3, u = (c & 7) ^ (row & 7);
        int ar = tm + row;
        int arow = (ar / S) * NTOK + seg_start + (ar % S);
        aptr[j] = (const short*)A + (size_t)arow * CC + u * 8;
        bptr[j] = W + (size_t)(tileN + row) * CC + u * 8;
    }

    f32x4 zero = {0.f, 0.f, 0.f, 0.f};
    f32x4 acc[4][4];
#pragma unroll
    for (int mb = 0; mb < 4; ++mb)
#pragma unroll
        for (int nb = 0; nb < 4; ++nb) acc[mb][nb] = zero;

    // prologue: stage K-tile 0 into buffer 0
#pragma unroll
    for (int j = 0; j < 4; ++j) {
        int c8 = (j * 256 + tid) * 8;
        GL_LDS(aptr[j], lds + c8);
        GL_LDS(bptr[j], lds + 8192 + c8);
    }
    __syncthreads();   // drains prologue vmcnt

    int cur = 0;
    for (int k0 = 64; k0 <= CC; k0 += 64) {
        short* As = lds + cur * 16384;
        short* Bs = As + 8192;
        if (k0 < CC) {   // prefetch next K-tile into the other buffer
            short* An = lds + (cur ^ 1) * 16384;
#pragma unroll
            for (int j = 0; j < 4; ++j) {
                int c8 = (j * 256 + tid) * 8;
                GL_LDS(aptr[j] + k0, An + c8);
                GL_LDS(bptr[j] + k0, An + 8192 + c8);
            }
        }

#pragma unroll
        for (int s = 0; s < 2; ++s) {
            int sx = ((s * 4 + quad) ^ r7) * 8;
            short8 af[4], bf[4];
#pragma unroll
            for (int mb = 0; mb < 4; ++mb)
                af[mb] = *(const short8*)&As[(wm * 64 + mb * 16 + l15) * 64 + sx];
#pragma unroll
            for (int nb = 0; nb < 4; ++nb)
                bf[nb] = *(const short8*)&Bs[(wn * 64 + nb * 16 + l15) * 64 + sx];
#pragma unroll
            for (int mb = 0; mb < 4; ++mb)
#pragma unroll
                for (int nb = 0; nb < 4; ++nb)
                    acc[mb][nb] = __builtin_amdgcn_mfma_f32_16x16x32_bf16(af[mb], bf[nb], acc[mb][nb], 0, 0, 0);
        }
        // single sync point: drains prefetch vmcnt + lgkm, frees As/Bs
        __syncthreads();
        cur ^= 1;
    }

    int sect = tileN >> 10;                    // 0=Q, 1=K, 2=V

    if (sect < 2) {
        const float* nw = (sect == 0 ? qn_w : kn_w) + seg * HD;
        const float* nbv = (sect == 0 ? qn_b : kn_b) + seg * HD;
        float lw[4], lb[4], bcol[4];
#pragma unroll
        for (int nb = 0; nb < 4; ++nb) {
            lw[nb] = nw[nb * 16 + l15];
            lb[nb] = nbv[nb * 16 + l15];
            bcol[nb] = bias[tileN + wn * 64 + nb * 16 + l15];
        }
        // 0.125 * log2(e): attention uses exp2
        float qscale = (sect == 0) ? 0.18033688011112042f : 1.0f;

        float invf0 = expf(-9.210340371976184f * (float)l15 * (1.0f / 32.0f));
        float invf1 = expf(-9.210340371976184f * (float)(16 + l15) * (1.0f / 32.0f));
        float cd0, sd0, cd1, sd1;
        sincosf(invf0, &sd0, &cd0);   // unit-step rotation
        sincosf(invf1, &sd1, &cd1);

#pragma unroll
        for (int mb = 0; mb < 4; ++mb) {
            // pos for r=0 of this (mb, quad) group; r=0..3 tokens are consecutive
            int tok0 = wm * 64 + mb * 16 + quad * 4;
            int ar0 = tm + tok0;
            int nloc0 = ar0 % S;                           // local within segment
            int pos0 = (seg == 0) ? nloc0 : (seg_start + nloc0 - NT);
            float c0, s0, c1, s1v;
            sincosf((float)pos0 * invf0, &s0, &c0);
            sincosf((float)pos0 * invf1, &s1v, &c1);

#pragma unroll
            for (int r = 0; r < 4; ++r) {
                int tok = tok0 + r;
                float v[4];
#pragma unroll
                for (int nb = 0; nb < 4; ++nb) v[nb] = acc[mb][nb][r] + bcol[nb];

                // one-pass LN: reduce (sum, sumsq) together
                float t1 = v[0] + v[1] + v[2] + v[3];
                float t2 = v[0] * v[0] + v[1] * v[1] + v[2] * v[2] + v[3] * v[3];
#pragma unroll
                for (int off = 8; off >= 1; off >>= 1) {
                    t1 += __shfl_xor(t1, off);
                    t2 += __shfl_xor(t2, off);
                }
                float mu = t1 * (1.0f / 64.0f);
                float var = t2 * (1.0f / 64.0f) - mu * mu;
                float rstd = rsqrtf(var + EPSV);
#pragma unroll
                for (int nb = 0; nb < 4; ++nb) v[nb] = (v[nb] - mu) * rstd * lw[nb] + lb[nb];

                short* bp = &buf[tok * 134 + wn * 64];
                bp[0 * 16 + l15] = bf16raw((v[0] * c0 - v[2] * s0) * qscale);
                bp[1 * 16 + l15] = bf16raw((v[1] * c1 - v[3] * s1v) * qscale);
                bp[2 * 16 + l15] = bf16raw((v[2] * c0 + v[0] * s0) * qscale);
                bp[3 * 16 + l15] = bf16raw((v[3] * c1 + v[1] * s1v) * qscale);

                // advance rotation to next consecutive position
                float nc0 = c0 * cd0 - s0 * sd0, ns0 = s0 * cd0 + c0 * sd0;
                float nc1 = c1 * cd1 - s1v * sd1, ns1 = s1v * cd1 + c1 * sd1;
                c0 = nc0; s0 = ns0; c1 = nc1; s1v = ns1;
            }
        }
        __syncthreads();
        __hip_bfloat16* dst = (sect == 0) ? Q : Kg;
        int head_base = (tileN & 1023) >> 6;
#pragma unroll
        for (int it = 0; it < 8; ++it) {
            int idx = it * 256 + tid;
            int tok = idx >> 4, cc = (idx & 15) * 8;
            int ar = tm + tok;
            int bb = ar / S;
            int nloc = seg_start + (ar % S);
            int hh2 = head_base + (cc >> 6), d = cc & 63;
            *(short8*)((short*)dst + ((size_t)(bb * HH + hh2) * NTOK + nloc) * HD + d) =
                *(const short8*)&buf[tok * 134 + cc];
        }
    } else {
        float bcol[4];
#pragma unroll
        for (int nb = 0; nb < 4; ++nb) bcol[nb] = bias[tileN + wn * 64 + nb * 16 + l15];
#pragma unroll
        for (int mb = 0; mb < 4; ++mb) {
#pragma unroll
            for (int r = 0; r < 4; ++r) {
                int tok = wm * 64 + mb * 16 + quad * 4 + r;
#pragma unroll
                for (int nb = 0; nb < 4; ++nb) {
                    int col = wn * 64 + nb * 16 + l15;
                    buf[col * 134 + tok] = bf16raw(acc[mb][nb][r] + bcol[nb]);
                }
            }
        }
        __syncthreads();
#pragma unroll
        for (int it = 0; it < 8; ++it) {
            int idx = it * 256 + tid;
            int row = idx >> 4;
            int tc = (idx & 15) * 8;
            int vcol = (tileN - 2048) + row;
            int h = vcol >> 6, d = vcol & 63;
            int ar = tm + tc;
            int bb = ar / S;
            int nloc = seg_start + (ar % S);
            short8 val = *(const short8*)&buf[row * 134 + tc];
            *(short8*)((short*)Vt + ((size_t)(bb * HH + h) * HD + d) * NTOK + nloc) = val;
        }
    }
}

// ---------------- proj GEMM: 64Mx128N tile, BK=64 swizzled, 2-phase dbuf ----
__global__ __launch_bounds__(256) void gemm_proj(
    const __hip_bfloat16* __restrict__ A,
    const __hip_bfloat16* __restrict__ Wb,    // (3, CC, CC)
    const float* __restrict__ biasb,          // (3, CC)
    float* __restrict__ Cout)
{
    // 48KB: buffer b at b*12288 shorts: [As 4096 | Bs 8192]
    __shared__ short lds[24576];

    int tid = threadIdx.x;
    int lane = tid & 63, w = tid >> 6;
    int l15 = lane & 15, quad = lane >> 4;
    int wm = w >> 1, wn = w & 1;
    int r7 = l15 & 7;

    int y = blockIdx.y;
    int seg, tm;
    if (y < 32)      { seg = 1; tm = y * 64; }
    else if (y < 64) { seg = 2; tm = (y - 32) * 64; }
    else             { seg = 0; tm = (y - 64) * 64; }
    int S = (seg == 0) ? 64 : 1024;
    int seg_start = (seg == 0) ? 0 : (seg == 1 ? NT : NT + NC);
    const short* W = (const short*)Wb + (size_t)seg * CC * CC;
    const float* bias = biasb + (size_t)seg * CC;
    int tileN = blockIdx.x * 128;

    const short* aptr[2];
    const short* bptr[4];
#pragma unroll
    for (int j = 0; j < 2; ++j) {
        int c = j * 256 + tid;
        int row = c >> 3, u = (c & 7) ^ (row & 7);
        int ar = tm + row;
        int arow = (ar / S) * NTOK + seg_start + (ar % S);
        aptr[j] = (const short*)A + (size_t)arow * CC + u * 8;
    }
#pragma unroll
    for (int j = 0; j < 4; ++j) {
        int c = j * 256 + tid;
        int row = c >> 3, u = (c & 7) ^ (row & 7);
        bptr[j] = W + (size_t)(tileN + row) * CC + u * 8;
    }

    f32x4 zero = {0.f, 0.f, 0.f, 0.f};
    f32x4 acc[2][4];
#pragma unroll
    for (int mb = 0; mb < 2; ++mb)
#pragma unroll
        for (int nb = 0; nb < 4; ++nb) acc[mb][nb] = zero;

    // prologue: stage tile 0 into buffer 0
#pragma unroll
    for (int j = 0; j < 2; ++j)
        GL_LDS(aptr[j], lds + (j * 256 + tid) * 8);
#pragma unroll
    for (int j = 0; j < 4; ++j)
        GL_LDS(bptr[j], lds + 4096 + (j * 256 + tid) * 8);
    __syncthreads();

    int cur = 0;
    for (int k0 = 64; k0 <= CC; k0 += 64) {
        short* As = lds + cur * 12288;
        short* Bs = As + 4096;
        if (k0 < CC) {
            short* An = lds + (cur ^ 1) * 12288;
#pragma unroll
            for (int j = 0; j < 2; ++j)
                GL_LDS(aptr[j] + k0, An + (j * 256 + tid) * 8);
#pragma unroll
            for (int j = 0; j < 4; ++j)
                GL_LDS(bptr[j] + k0, An + 4096 + (j * 256 + tid) * 8);
        }

#pragma unroll
        for (int s = 0; s < 2; ++s) {
            int sx = ((s * 4 + quad) ^ r7) * 8;
            short8 af[2], bf[4];
#pragma unroll
            for (int mb = 0; mb < 2; ++mb)
                af[mb] = *(const short8*)&As[(wm * 32 + mb * 16 + l15) * 64 + sx];
#pragma unroll
            for (int nb = 0; nb < 4; ++nb)
                bf[nb] = *(const short8*)&Bs[(wn * 64 + nb * 16 + l15) * 64 + sx];
#pragma unroll
            for (int mb = 0; mb < 2; ++mb)
#pragma unroll
                for (int nb = 0; nb < 4; ++nb)
                    acc[mb][nb] = __builtin_amdgcn_mfma_f32_16x16x32_bf16(af[mb], bf[nb], acc[mb][nb], 0, 0, 0);
        }
        __syncthreads();
        cur ^= 1;
    }

#pragma unroll
    for (int mb = 0; mb < 2; ++mb) {
#pragma unroll
        for (int r = 0; r < 4; ++r) {
            int ar = tm + wm * 32 + mb * 16 + quad * 4 + r;
            int crow = (ar / S) * NTOK + seg_start + (ar % S);
            float* cp = Cout + (size_t)crow * CC + tileN;
#pragma unroll
            for (int nb = 0; nb < 4; ++nb) {
                int col = wn * 64 + nb * 16 + l15;
                cp[col] = acc[mb][nb][r] + bias[tileN + col];
            }
        }
    }
}

// ---------------- split-K MFMA flash attention, 2-phase K/V dbuf ----------------
// exp2 softmax (Q pre-scaled by 0.125*log2e); interior-tile mask elision;
// setprio around MFMA clusters.
__global__ __launch_bounds__(512) void attn_part(
    const __hip_bfloat16* __restrict__ Q,
    const __hip_bfloat16* __restrict__ Kg,
    const __hip_bfloat16* __restrict__ Vt,
    __hip_bfloat16* __restrict__ O,
    float* __restrict__ Opart,        // [32*17*3][128*64]
    float* __restrict__ lpart)        // [32*17*3][128]
{
    __shared__ short Ks[2][4096];
    __shared__ short Vs[2][4096];
    __shared__ short Ps[8][16 * 72];

    int tid = threadIdx.x;
    int lane = tid & 63, w = tid >> 6;
    int quad = lane >> 4, l15 = lane & 15;
    int r7 = l15 & 7;
    int bh = blockIdx.y, b = bh >> 4, h = bh & 15;

    int e = blockIdx.x;
    int qb = QB_tab[e], c = CH_tab[e];
    int q0 = qb * 128;
    int nt = 2 * qb + 2; if (nt > 33) nt = 33;
    int t0 = c * 12, t1 = t0 + 12; if (t1 > nt) t1 = nt;
    bool direct = (nt <= 12);

    size_t base = (size_t)bh * NTOK * HD;

    int qrow = q0 + w * 16 + l15;
    int qr_c = qrow < NTOK ? qrow : NTOK - 1;
    short8 qf0 = *(const short8*)((const short*)Q + base + (size_t)qr_c * HD + quad * 8);
    short8 qf1 = *(const short8*)((const short*)Q + base + (size_t)qr_c * HD + 32 + quad * 8);

    int srow = tid >> 3;
    int su = (tid & 7) ^ (srow & 7);
    const short* kptr = (const short*)Kg + base + (size_t)srow * HD + su * 8;
    const short* vptr = (const short*)Vt + base + (size_t)srow * NTOK + su * 8;
    int c8 = tid * 8;

    f32x4 zero = {0.f, 0.f, 0.f, 0.f};
    f32x4 oacc[4] = {zero, zero, zero, zero};
    float l[4] = {0.f, 0.f, 0.f, 0.f};

    int qmin_w = q0 + w * 16;
    int qmax_w = qmin_w + 15;
    int sx0 = (quad ^ r7) * 8;
    int sx1 = ((4 + quad) ^ r7) * 8;

    // prologue: stage tile t0 into buffer 0
    GL_LDS(kptr + (size_t)(t0 * 64) * HD, Ks[0] + c8);
    GL_LDS(vptr + t0 * 64, Vs[0] + c8);
    __syncthreads();

    int cur = 0;
    for (int t = t0; t < t1; ++t) {
        if (t + 1 < t1) {   // prefetch next K/V tile
            GL_LDS(kptr + (size_t)((t + 1) * 64) * HD, Ks[cur ^ 1] + c8);
            GL_LDS(vptr + (t + 1) * 64, Vs[cur ^ 1] + c8);
        }

        if (t * 64 <= qmax_w) {
            f32x4 s[4];
            __builtin_amdgcn_s_setprio(1);
#pragma unroll
            for (int kb = 0; kb < 4; ++kb) {
                int krow = (kb * 16 + l15) * 64;
                short8 kf0 = *(const short8*)&Ks[cur][krow + sx0];
                short8 kf1 = *(const short8*)&Ks[cur][krow + sx1];
                f32x4 z = zero;
                z = __builtin_amdgcn_mfma_f32_16x16x32_bf16(qf0, kf0, z, 0, 0, 0);
                z = __builtin_amdgcn_mfma_f32_16x16x32_bf16(qf1, kf1, z, 0, 0, 0);
                s[kb] = z;
            }
            __builtin_amdgcn_s_setprio(0);

            if (t * 64 + 63 <= qmin_w) {
                // interior tile: fully causal for every row of this wave — no mask
#pragma unroll
                for (int r = 0; r < 4; ++r)
#pragma unroll
                    for (int kb = 0; kb < 4; ++kb) {
                        float p = __builtin_amdgcn_exp2f(s[kb][r]);
                        Ps[w][(quad * 4 + r) * 72 + kb * 16 + l15] = bf16raw(p);
                        l[r] += p;
                    }
            } else {
#pragma unroll
                for (int r = 0; r < 4; ++r) {
                    int qg = q0 + w * 16 + quad * 4 + r;
#pragma unroll
                    for (int kb = 0; kb < 4; ++kb) {
                        int kgk = t * 64 + kb * 16 + l15;
                        float p = (kgk <= qg) ? __builtin_amdgcn_exp2f(s[kb][r]) : 0.f;
                        Ps[w][(quad * 4 + r) * 72 + kb * 16 + l15] = bf16raw(p);
                        l[r] += p;
                    }
                }
            }

            __builtin_amdgcn_wave_barrier();

            __builtin_amdgcn_s_setprio(1);
#pragma unroll
            for (int sl = 0; sl < 2; ++sl) {
                short8 pf = *(const short8*)&Ps[w][l15 * 72 + sl * 32 + quad * 8];
                int vsx = ((sl * 4 + quad) ^ r7) * 8;
#pragma unroll
                for (int db = 0; db < 4; ++db) {
                    short8 vf = *(const short8*)&Vs[cur][(db * 16 + l15) * 64 + vsx];
                    oacc[db] = __builtin_amdgcn_mfma_f32_16x16x32_bf16(pf, vf, oacc[db], 0, 0, 0);
                }
            }
            __builtin_amdgcn_s_setprio(0);
        }

        __syncthreads();   // drains prefetch, frees Ks/Vs[cur]
        cur ^= 1;
    }

#pragma unroll
    for (int r = 0; r < 4; ++r) {
#pragma unroll
        for (int off = 8; off >= 1; off >>= 1) l[r] += __shfl_xor(l[r], off);
    }

    if (direct) {
#pragma unroll
        for (int r = 0; r < 4; ++r) {
            int qg = q0 + w * 16 + quad * 4 + r;
            float inv_l = 1.0f / l[r];
#pragma unroll
            for (int db = 0; db < 4; ++db) {
                O[(size_t)(b * NTOK + qg) * CC + h * HD + db * 16 + l15] =
                    __float2bfloat16(oacc[db][r] * inv_l);
            }
        }
    } else {
        int pidx = (bh * 17 + qb) * 3 + c;
        float* op = Opart + (size_t)pidx * (128 * 64);
#pragma unroll
        for (int r = 0; r < 4; ++r) {
            int q = w * 16 + quad * 4 + r;
#pragma unroll
            for (int db = 0; db < 4; ++db)
                op[q * 64 + db * 16 + l15] = oacc[db][r];
            if (l15 == 0) lpart[pidx * 128 + q] = l[r];
        }
    }
}

// ---------------- combine partials: float4-vectorized sum + normalize + bf16 ----
__global__ __launch_bounds__(512) void attn_comb(
    const float* __restrict__ Opart, const float* __restrict__ lpart,
    __hip_bfloat16* __restrict__ O)
{
    __shared__ float ls[128];
    int tid = threadIdx.x;
    int qb = 6 + blockIdx.x;
    int bh = blockIdx.y, b = bh >> 4, h = bh & 15;
    int nt = 2 * qb + 2; if (nt > 33) nt = 33;
    int nch = (nt + 11) / 12;
    int q0 = qb * 128;
    int pbase = (bh * 17 + qb) * 3;

    if (tid < 128) {
        float s = 0.f;
        for (int cc = 0; cc < nch; ++cc) s += lpart[(pbase + cc) * 128 + tid];
        ls[tid] = 1.0f / s;
    }
    __syncthreads();

    // 8192 floats per (bh,qb) tile = 2048 float4s; 512 threads x 4 iters
#pragma unroll
    for (int k = 0; k < 4; ++k) {
        int e4 = k * 512 + tid;           // float4 index in [0, 2048)
        int q = e4 >> 4;                  // (e4*4) / 64
        int d4 = (e4 & 15) * 4;           // first of 4 consecutive dims
        int qg = q0 + q;
        if (qg >= NTOK) continue;
        float4v s = {0.f, 0.f, 0.f, 0.f};
        for (int cc = 0; cc < nch; ++cc) {
            float4v a = *(const float4v*)(Opart + (size_t)(pbase + cc) * 8192 + e4 * 4);
            s.x += a.x; s.y += a.y; s.z += a.z; s.w += a.w;
        }
        float inv = ls[q];
        short4 o;
        o.x = bf16raw(s.x * inv); o.y = bf16raw(s.y * inv);
        o.z = bf16raw(s.z * inv); o.w = bf16raw(s.w * inv);
        *(short4*)((short*)O + (size_t)(b * NTOK + qg) * CC + h * HD + d4) = o;
    }
}

// ---------------- launch ----------------
extern "C" void kernel_launch(void* const* d_in, const int* in_sizes, int n_in,
                              void* d_out, int out_size, void* d_ws, size_t ws_size,
                              hipStream_t stream) {
    const float* x      = (const float*)d_in[0];
    const float* qkv_w  = (const float*)d_in[7];
    const float* qkv_b  = (const float*)d_in[8];
    const float* qn_w   = (const float*)d_in[9];
    const float* qn_b   = (const float*)d_in[10];
    const float* kn_w   = (const float*)d_in[11];
    const float* kn_b   = (const float*)d_in[12];
    const float* proj_w = (const float*)d_in[13];
    const float* proj_b = (const float*)d_in[14];
    float* out = (float*)d_out;

    const size_t n_x    = (size_t)BB * NTOK * CC;
    const size_t n_qkvw = (size_t)3 * K3 * CC;
    const size_t n_prjw = (size_t)3 * CC * CC;
    const size_t n_part = (size_t)32 * 17 * 3;

    __hip_bfloat16* x_bf    = (__hip_bfloat16*)d_ws;
    __hip_bfloat16* qkvw_bf = x_bf + n_x;
    __hip_bfloat16* prjw_bf = qkvw_bf + n_qkvw;
    __hip_bfloat16* Qbf  = prjw_bf + n_prjw;
    __hip_bfloat16* Kbf  = Qbf + n_x;
    __hip_bfloat16* Vtbf = Kbf + n_x;
    float* Opart = (float*)(Vtbf + n_x);
    float* lpart = Opart + n_part * (128 * 64);
    __hip_bfloat16* attn_bf = x_bf;   // reuse: x_bf dead after gemm_qkv

    cast_all<<<1024, 256, 0, stream>>>(x, qkv_w, proj_w, x_bf, qkvw_bf, prjw_bf,
                                       (int)(n_x / 4), (int)(n_qkvw / 4), (int)(n_prjw / 4));

    gemm_qkv<<<dim3(K3 / 128, 33), 256, 0, stream>>>(
        x_bf, qkvw_bf, qkv_b,
        qn_w, qn_b, kn_w, kn_b, Qbf, Kbf, Vtbf);

    attn_part<<<dim3(33, BB * HH), 512, 0, stream>>>(Qbf, Kbf, Vtbf, attn_bf, Opart, lpart);

    attn_comb<<<dim3(11, BB * HH), 512, 0, stream>>>(Opart, lpart, attn_bf);

    gemm_proj<<<dim3(CC / 128, 66), 256, 0, stream>>>(attn_bf, prjw_bf, proj_b, out);
}